// Round 6
// baseline (111.420 us; speedup 1.0000x reference)
//
#include <hip/hip_runtime.h>
#include <math.h>

#define N_NODES 512
#define BATCH   8
#define SEQ     512
#define NDIM    10
#define CC      16
#define SC      16
#define TOPK    4
#define ALPHA   0.05f
#define LN_EPS  1e-5f
#define ROWS_PER_BLOCK 4

// ---- workspace layout ----
// int region   : nidx[4][512]                      (elements 0..2047 as int)
// float region : nw[4][512]    at OFF_NW
//                wself[512]    at OFF_WSELF
//                u[3][16]      at OFF_U      (contiguous through bend)
//                beta[16]      at OFF_BETA
//                wend[16]      at OFF_WEND
//                bend[1]       at OFF_BEND
#define OFF_NW    2048
#define OFF_WSELF 4096
#define OFF_U     4608
#define OFF_BETA  4656
#define OFF_WEND  4672
#define OFF_BEND  4688
#define N_CONST   81   // 48 u + 16 beta + 16 wend + 1 bend, contiguous from OFF_U

// ---------------------------------------------------------------------------
// Kernel 1: sparse adjacency build (one wave per row) + weight folding
// ---------------------------------------------------------------------------
__global__ __launch_bounds__(64) void prep_kernel(
    const float* __restrict__ nodevec,   // [512,10]
    const float* __restrict__ nodeveck,  // [1,10]
    const float* __restrict__ w_start,   // [16,1]
    const float* __restrict__ b_start,   // [16]
    const float* __restrict__ w_mlp,     // [16,48]
    const float* __restrict__ b_mlp,     // [16]
    const float* __restrict__ w_end,     // [1,16]
    const float* __restrict__ b_end,     // [1]
    int*   __restrict__ wsI,
    float* __restrict__ wsF)
{
    const int v    = blockIdx.x;
    const int lane = threadIdx.x;

    if (v == N_NODES) {
        // ---- weight folding block ----
        if (lane < SC) {
            const int o = lane;
            float u0 = 0.f, u1 = 0.f, u2 = 0.f, bt = b_mlp[o];
            for (int c = 0; c < CC; ++c) {
                const float ws = w_start[c];
                const float bs = b_start[c];
                const float m0 = w_mlp[o * 48 + c];
                const float m1 = w_mlp[o * 48 + 16 + c];
                const float m2 = w_mlp[o * 48 + 32 + c];
                u0 += m0 * ws; u1 += m1 * ws; u2 += m2 * ws;
                bt += (m0 + m1 + m2) * bs;
            }
            wsF[OFF_U + 0 * 16 + o] = u0;
            wsF[OFF_U + 1 * 16 + o] = u1;
            wsF[OFF_U + 2 * 16 + o] = u2;
            wsF[OFF_BETA + o]       = bt;
            wsF[OFF_WEND + o]       = w_end[o];
            if (o == 0) wsF[OFF_BEND] = b_end[0];
        }
        return;
    }

    // q[d] = nodevec[v,d] * k[d]^2  so that  nv[v]·nv[w] = sum_d q[d]*nodevec[w,d]
    float q[NDIM];
    #pragma unroll
    for (int d = 0; d < NDIM; ++d) {
        const float k = nodeveck[d];
        q[d] = nodevec[v * NDIM + d] * k * k;
    }

    // each lane: 8 columns, relu(dot)
    float s[8];
    int   wi[8];
    #pragma unroll
    for (int j = 0; j < 8; ++j) {
        const int w = lane + 64 * j;
        wi[j] = w;
        float dot = 0.f;
        #pragma unroll
        for (int d = 0; d < NDIM; ++d) dot += q[d] * nodevec[w * NDIM + d];
        s[j] = dot > 0.f ? dot : 0.f;
    }

    // row max (for stable softmax)
    float m = s[0];
    #pragma unroll
    for (int j = 1; j < 8; ++j) m = fmaxf(m, s[j]);
    for (int off = 32; off; off >>= 1) m = fmaxf(m, __shfl_down(m, off));
    m = __shfl(m, 0);

    // softmax denominator over the full row
    float zs = 0.f;
    #pragma unroll
    for (int j = 0; j < 8; ++j) zs += expf(s[j] - m);
    for (int off = 32; off; off >>= 1) zs += __shfl_down(zs, off);
    zs = __shfl(zs, 0);

    // top-4 by 4 rounds of wave argmax (ties -> lowest index, matching lax.top_k)
    float sl[8];
    #pragma unroll
    for (int j = 0; j < 8; ++j) sl[j] = s[j];

    float topv[TOPK];
    int   topi[TOPK];
    for (int t = 0; t < TOPK; ++t) {
        float bv = -1.f; int bi = N_NODES;
        #pragma unroll
        for (int j = 0; j < 8; ++j) {
            if (sl[j] > bv || (sl[j] == bv && wi[j] < bi)) { bv = sl[j]; bi = wi[j]; }
        }
        for (int off = 32; off; off >>= 1) {
            const float ov = __shfl_down(bv, off);
            const int   oi = __shfl_down(bi, off);
            if (ov > bv || (ov == bv && oi < bi)) { bv = ov; bi = oi; }
        }
        bv = __shfl(bv, 0); bi = __shfl(bi, 0);
        topv[t] = bv; topi[t] = bi;
        #pragma unroll
        for (int j = 0; j < 8; ++j) if (wi[j] == bi) sl[j] = -1.f;
    }

    if (lane == 0) {
        float p[TOPK], rs = 1.f;  // +1 from the identity self-loop
        #pragma unroll
        for (int t = 0; t < TOPK; ++t) { p[t] = expf(topv[t] - m) / zs; rs += p[t]; }
        const float inv = 1.f / rs;
        #pragma unroll
        for (int t = 0; t < TOPK; ++t) {
            wsI[t * N_NODES + v]          = topi[t];
            wsF[OFF_NW + t * N_NODES + v] = p[t] * inv;
        }
        wsF[OFF_WSELF + v] = inv;
    }
}

// ---------------------------------------------------------------------------
// Kernel 2: one block per ROWS_PER_BLOCK (b,l) rows. Adjacency/constants are
// loaded once per block; per row: sparse diffusion + fused mlp/gelu/end conv
// + residual + LayerNorm over N.
// Barrier audit (3 per row, race-free): s_x0 reads < B(r); s_x1 reads and
// s_red writes < C(r); s_red reads < A(r+1) in program order; next row's
// writes to s_x0/s_x1/s_red all occur after A(r+1)/B(r+1).
// ---------------------------------------------------------------------------
__global__ __launch_bounds__(512) void graphblock_kernel(
    const float* __restrict__ x,         // [B, L, N]
    const float* __restrict__ ln_gamma,  // [N]
    const float* __restrict__ ln_beta,   // [N]
    const int*   __restrict__ wsI,
    const float* __restrict__ wsF,
    float*       __restrict__ out)       // [B, L, N]
{
    __shared__ float s_x0[N_NODES];
    __shared__ float s_x1[N_NODES];
    __shared__ float s_c[N_CONST];
    __shared__ float s_red[16];

    const int tid  = threadIdx.x;                       // node index v
    const int row0 = blockIdx.x * ROWS_PER_BLOCK;       // first (b*SEQ+l) row

    if (tid < N_CONST) s_c[tid] = wsF[OFF_U + tid];

    // ---- block-invariant per-thread data (hoisted out of the row loop) ----
    const int   i0 = wsI[0 * N_NODES + tid];
    const int   i1 = wsI[1 * N_NODES + tid];
    const int   i2 = wsI[2 * N_NODES + tid];
    const int   i3 = wsI[3 * N_NODES + tid];
    const float a0 = wsF[OFF_NW + 0 * N_NODES + tid];
    const float a1 = wsF[OFF_NW + 1 * N_NODES + tid];
    const float a2 = wsF[OFF_NW + 2 * N_NODES + tid];
    const float a3 = wsF[OFF_NW + 3 * N_NODES + tid];
    const float as = wsF[OFF_WSELF + tid];
    const float gam = ln_gamma[tid];
    const float bet = ln_beta[tid];

    const float one_m_alpha = 1.f - ALPHA;

    for (int r = 0; r < ROWS_PER_BLOCK; ++r) {
        const size_t row = (size_t)(row0 + r);
        const float x0 = x[row * N_NODES + tid];
        s_x0[tid] = x0;
        __syncthreads();                                // A(r)

        // diffusion step 1
        float g = a0 * s_x0[i0] + a1 * s_x0[i1] + a2 * s_x0[i2] + a3 * s_x0[i3] + as * x0;
        const float x1 = ALPHA * x0 + one_m_alpha * g;
        s_x1[tid] = x1;
        __syncthreads();                                // B(r)

        // diffusion step 2
        g = a0 * s_x1[i0] + a1 * s_x1[i1] + a2 * s_x1[i2] + a3 * s_x1[i3] + as * x1;
        const float x2 = ALPHA * x0 + one_m_alpha * g;

        // folded mlp (16 out channels) + exact gelu + end 1x1 conv
        float acc = s_c[80];  // b_end
        #pragma unroll
        for (int o = 0; o < SC; ++o) {
            const float t = s_c[o] * x0 + s_c[16 + o] * x1 + s_c[32 + o] * x2 + s_c[48 + o];
            const float ge = 0.5f * t * (1.f + erff(t * 0.70710678118654752440f));
            acc += s_c[64 + o] * ge;
        }

        const float y = x0 + acc;

        // LayerNorm over the 512 nodes of this row
        float sum = y, sumsq = y * y;
        for (int off = 32; off; off >>= 1) {
            sum   += __shfl_down(sum, off);
            sumsq += __shfl_down(sumsq, off);
        }
        const int wv = tid >> 6;
        if ((tid & 63) == 0) { s_red[wv] = sum; s_red[8 + wv] = sumsq; }
        __syncthreads();                                // C(r)

        float ts = 0.f, tq = 0.f;
        #pragma unroll
        for (int i = 0; i < 8; ++i) { ts += s_red[i]; tq += s_red[8 + i]; }
        const float mu   = ts * (1.f / (float)N_NODES);
        const float var  = tq * (1.f / (float)N_NODES) - mu * mu;
        const float rstd = 1.0f / sqrtf(var + LN_EPS);

        out[row * N_NODES + tid] = (y - mu) * rstd * gam + bet;
    }
}

// ---------------------------------------------------------------------------
extern "C" void kernel_launch(void* const* d_in, const int* in_sizes, int n_in,
                              void* d_out, int out_size, void* d_ws, size_t ws_size,
                              hipStream_t stream) {
    const float* x        = (const float*)d_in[0];
    const float* nodevec  = (const float*)d_in[1];
    const float* nodeveck = (const float*)d_in[2];
    const float* w_start  = (const float*)d_in[3];
    const float* b_start  = (const float*)d_in[4];
    const float* w_mlp    = (const float*)d_in[5];
    const float* b_mlp    = (const float*)d_in[6];
    const float* w_end    = (const float*)d_in[7];
    const float* b_end    = (const float*)d_in[8];
    const float* ln_gamma = (const float*)d_in[9];
    const float* ln_beta  = (const float*)d_in[10];

    int*   wsI = (int*)d_ws;
    float* wsF = (float*)d_ws;

    prep_kernel<<<N_NODES + 1, 64, 0, stream>>>(
        nodevec, nodeveck, w_start, b_start, w_mlp, b_mlp, w_end, b_end, wsI, wsF);

    graphblock_kernel<<<(BATCH * SEQ) / ROWS_PER_BLOCK, 512, 0, stream>>>(
        x, ln_gamma, ln_beta, (const int*)d_ws, (const float*)d_ws, (float*)d_out);
}

// Round 7
// 108.026 us; speedup vs baseline: 1.0314x; 1.0314x over previous
//
#include <hip/hip_runtime.h>
#include <math.h>

#define N_NODES 512
#define BATCH   8
#define SEQ     512
#define NDIM    10
#define CC      16
#define SC      16
#define TOPK    4
#define ALPHA   0.05f
#define LN_EPS  1e-5f
#define ROWS_PER_BLOCK 4

// ---- workspace layout ----
#define OFF_NW    2048
#define OFF_WSELF 4096
#define OFF_U     4608
#define OFF_BETA  4656
#define OFF_WEND  4672
#define OFF_BEND  4688
#define N_CONST   81   // 48 u + 16 beta + 16 wend + 1 bend, contiguous from OFF_U

// ---------------------------------------------------------------------------
// Branchless exact-GELU: 0.5*t*(1+erf(t/sqrt2)) with A&S 7.1.26 erf
// (|err| <= 1.5e-7, far below the 7.8e-3 absmax slack). exp(-z^2) = exp(-t^2/2).
// ---------------------------------------------------------------------------
__device__ __forceinline__ float gelu_exact_fast(float t) {
    const float z = fabsf(t) * 0.70710678118654752440f;
    const float e = __expf(-0.5f * t * t);
    const float r = __builtin_amdgcn_rcpf(fmaf(0.3275911f, z, 1.0f));
    float p = fmaf(1.061405429f, r, -1.453152027f);
    p = fmaf(p, r, 1.421413741f);
    p = fmaf(p, r, -0.284496736f);
    p = fmaf(p, r, 0.254829592f);
    p = p * r;
    const float erfz = 1.0f - p * e;          // erf(|t|/sqrt2) >= 0
    return 0.5f * t * (1.0f + copysignf(erfz, t));
}

// ---------------------------------------------------------------------------
// Kernel 1: sparse adjacency build (one wave per row) + weight folding
// ---------------------------------------------------------------------------
__global__ __launch_bounds__(64) void prep_kernel(
    const float* __restrict__ nodevec,   // [512,10]
    const float* __restrict__ nodeveck,  // [1,10]
    const float* __restrict__ w_start,   // [16,1]
    const float* __restrict__ b_start,   // [16]
    const float* __restrict__ w_mlp,     // [16,48]
    const float* __restrict__ b_mlp,     // [16]
    const float* __restrict__ w_end,     // [1,16]
    const float* __restrict__ b_end,     // [1]
    int*   __restrict__ wsI,
    float* __restrict__ wsF)
{
    const int v    = blockIdx.x;
    const int lane = threadIdx.x;

    if (v == N_NODES) {
        if (lane < SC) {
            const int o = lane;
            float u0 = 0.f, u1 = 0.f, u2 = 0.f, bt = b_mlp[o];
            for (int c = 0; c < CC; ++c) {
                const float ws = w_start[c];
                const float bs = b_start[c];
                const float m0 = w_mlp[o * 48 + c];
                const float m1 = w_mlp[o * 48 + 16 + c];
                const float m2 = w_mlp[o * 48 + 32 + c];
                u0 += m0 * ws; u1 += m1 * ws; u2 += m2 * ws;
                bt += (m0 + m1 + m2) * bs;
            }
            wsF[OFF_U + 0 * 16 + o] = u0;
            wsF[OFF_U + 1 * 16 + o] = u1;
            wsF[OFF_U + 2 * 16 + o] = u2;
            wsF[OFF_BETA + o]       = bt;
            wsF[OFF_WEND + o]       = w_end[o];
            if (o == 0) wsF[OFF_BEND] = b_end[0];
        }
        return;
    }

    float q[NDIM];
    #pragma unroll
    for (int d = 0; d < NDIM; ++d) {
        const float k = nodeveck[d];
        q[d] = nodevec[v * NDIM + d] * k * k;
    }

    float s[8];
    int   wi[8];
    #pragma unroll
    for (int j = 0; j < 8; ++j) {
        const int w = lane + 64 * j;
        wi[j] = w;
        float dot = 0.f;
        #pragma unroll
        for (int d = 0; d < NDIM; ++d) dot += q[d] * nodevec[w * NDIM + d];
        s[j] = dot > 0.f ? dot : 0.f;
    }

    float m = s[0];
    #pragma unroll
    for (int j = 1; j < 8; ++j) m = fmaxf(m, s[j]);
    for (int off = 32; off; off >>= 1) m = fmaxf(m, __shfl_down(m, off));
    m = __shfl(m, 0);

    float zs = 0.f;
    #pragma unroll
    for (int j = 0; j < 8; ++j) zs += expf(s[j] - m);
    for (int off = 32; off; off >>= 1) zs += __shfl_down(zs, off);
    zs = __shfl(zs, 0);

    float sl[8];
    #pragma unroll
    for (int j = 0; j < 8; ++j) sl[j] = s[j];

    float topv[TOPK];
    int   topi[TOPK];
    for (int t = 0; t < TOPK; ++t) {
        float bv = -1.f; int bi = N_NODES;
        #pragma unroll
        for (int j = 0; j < 8; ++j) {
            if (sl[j] > bv || (sl[j] == bv && wi[j] < bi)) { bv = sl[j]; bi = wi[j]; }
        }
        for (int off = 32; off; off >>= 1) {
            const float ov = __shfl_down(bv, off);
            const int   oi = __shfl_down(bi, off);
            if (ov > bv || (ov == bv && oi < bi)) { bv = ov; bi = oi; }
        }
        bv = __shfl(bv, 0); bi = __shfl(bi, 0);
        topv[t] = bv; topi[t] = bi;
        #pragma unroll
        for (int j = 0; j < 8; ++j) if (wi[j] == bi) sl[j] = -1.f;
    }

    if (lane == 0) {
        float p[TOPK], rs = 1.f;  // +1 from the identity self-loop
        #pragma unroll
        for (int t = 0; t < TOPK; ++t) { p[t] = expf(topv[t] - m) / zs; rs += p[t]; }
        const float inv = 1.f / rs;
        #pragma unroll
        for (int t = 0; t < TOPK; ++t) {
            wsI[t * N_NODES + v]          = topi[t];
            wsF[OFF_NW + t * N_NODES + v] = p[t] * inv;
        }
        wsF[OFF_WSELF + v] = inv;
    }
}

// ---------------------------------------------------------------------------
// Kernel 2: one block per ROWS_PER_BLOCK (b,l) rows. Adjacency/constants are
// loaded once per block; per row: sparse diffusion + fused mlp/gelu/end conv
// + residual + LayerNorm over N. 3 barriers/row (race audit in round 6).
// ---------------------------------------------------------------------------
__global__ __launch_bounds__(512) void graphblock_kernel(
    const float* __restrict__ x,         // [B, L, N]
    const float* __restrict__ ln_gamma,  // [N]
    const float* __restrict__ ln_beta,   // [N]
    const int*   __restrict__ wsI,
    const float* __restrict__ wsF,
    float*       __restrict__ out)       // [B, L, N]
{
    __shared__ float s_x0[N_NODES];
    __shared__ float s_x1[N_NODES];
    __shared__ float s_c[N_CONST];
    __shared__ float s_red[16];

    const int tid  = threadIdx.x;                       // node index v
    const int row0 = blockIdx.x * ROWS_PER_BLOCK;       // first (b*SEQ+l) row

    if (tid < N_CONST) s_c[tid] = wsF[OFF_U + tid];

    const int   i0 = wsI[0 * N_NODES + tid];
    const int   i1 = wsI[1 * N_NODES + tid];
    const int   i2 = wsI[2 * N_NODES + tid];
    const int   i3 = wsI[3 * N_NODES + tid];
    const float a0 = wsF[OFF_NW + 0 * N_NODES + tid];
    const float a1 = wsF[OFF_NW + 1 * N_NODES + tid];
    const float a2 = wsF[OFF_NW + 2 * N_NODES + tid];
    const float a3 = wsF[OFF_NW + 3 * N_NODES + tid];
    const float as = wsF[OFF_WSELF + tid];
    const float gam = ln_gamma[tid];
    const float bet = ln_beta[tid];

    const float one_m_alpha = 1.f - ALPHA;

    for (int r = 0; r < ROWS_PER_BLOCK; ++r) {
        const size_t row = (size_t)(row0 + r);
        const float x0 = x[row * N_NODES + tid];
        s_x0[tid] = x0;
        __syncthreads();                                // A(r)

        float g = a0 * s_x0[i0] + a1 * s_x0[i1] + a2 * s_x0[i2] + a3 * s_x0[i3] + as * x0;
        const float x1 = ALPHA * x0 + one_m_alpha * g;
        s_x1[tid] = x1;
        __syncthreads();                                // B(r)

        g = a0 * s_x1[i0] + a1 * s_x1[i1] + a2 * s_x1[i2] + a3 * s_x1[i3] + as * x1;
        const float x2 = ALPHA * x0 + one_m_alpha * g;

        float acc = s_c[80];  // b_end
        #pragma unroll
        for (int o = 0; o < SC; ++o) {
            const float t = s_c[o] * x0 + s_c[16 + o] * x1 + s_c[32 + o] * x2 + s_c[48 + o];
            acc += s_c[64 + o] * gelu_exact_fast(t);
        }

        const float y = x0 + acc;

        float sum = y, sumsq = y * y;
        for (int off = 32; off; off >>= 1) {
            sum   += __shfl_down(sum, off);
            sumsq += __shfl_down(sumsq, off);
        }
        const int wv = tid >> 6;
        if ((tid & 63) == 0) { s_red[wv] = sum; s_red[8 + wv] = sumsq; }
        __syncthreads();                                // C(r)

        float ts = 0.f, tq = 0.f;
        #pragma unroll
        for (int i = 0; i < 8; ++i) { ts += s_red[i]; tq += s_red[8 + i]; }
        const float mu   = ts * (1.f / (float)N_NODES);
        const float var  = tq * (1.f / (float)N_NODES) - mu * mu;
        const float rstd = 1.0f / sqrtf(var + LN_EPS);

        out[row * N_NODES + tid] = (y - mu) * rstd * gam + bet;
    }
}

// ---------------------------------------------------------------------------
extern "C" void kernel_launch(void* const* d_in, const int* in_sizes, int n_in,
                              void* d_out, int out_size, void* d_ws, size_t ws_size,
                              hipStream_t stream) {
    const float* x        = (const float*)d_in[0];
    const float* nodevec  = (const float*)d_in[1];
    const float* nodeveck = (const float*)d_in[2];
    const float* w_start  = (const float*)d_in[3];
    const float* b_start  = (const float*)d_in[4];
    const float* w_mlp    = (const float*)d_in[5];
    const float* b_mlp    = (const float*)d_in[6];
    const float* w_end    = (const float*)d_in[7];
    const float* b_end    = (const float*)d_in[8];
    const float* ln_gamma = (const float*)d_in[9];
    const float* ln_beta  = (const float*)d_in[10];

    int*   wsI = (int*)d_ws;
    float* wsF = (float*)d_ws;

    prep_kernel<<<N_NODES + 1, 64, 0, stream>>>(
        nodevec, nodeveck, w_start, b_start, w_mlp, b_mlp, w_end, b_end, wsI, wsF);

    graphblock_kernel<<<(BATCH * SEQ) / ROWS_PER_BLOCK, 512, 0, stream>>>(
        x, ln_gamma, ln_beta, (const int*)d_ws, (const float*)d_ws, (float*)d_out);
}

// Round 8
// 107.544 us; speedup vs baseline: 1.0360x; 1.0045x over previous
//
#include <hip/hip_runtime.h>
#include <math.h>

#define N_NODES 512
#define BATCH   8
#define SEQ     512
#define NDIM    10
#define CC      16
#define SC      16
#define TOPK    4
#define ALPHA   0.05f
#define LN_EPS  1e-5f
#define WAVES_PER_BLOCK 4
#define NODES_PER_LANE  8   // 512 nodes / 64 lanes

// ---- workspace layout (floats unless noted) ----
#define OFF_NW    2048   // nw[4][512]
#define OFF_WSELF 4096   // wself[512]
#define OFF_U     4608   // u[3][16]
#define OFF_BETA  4656   // beta[16]
#define OFF_WEND  4672   // wend[16]
#define OFF_BEND  4688   // bend[1]

// ---------------------------------------------------------------------------
// Branchless exact-GELU (A&S 7.1.26 erf, |err|<=1.5e-7) — validated round 7.
// ---------------------------------------------------------------------------
__device__ __forceinline__ float gelu_exact_fast(float t) {
    const float z = fabsf(t) * 0.70710678118654752440f;
    const float e = __expf(-0.5f * t * t);
    const float r = __builtin_amdgcn_rcpf(fmaf(0.3275911f, z, 1.0f));
    float p = fmaf(1.061405429f, r, -1.453152027f);
    p = fmaf(p, r, 1.421413741f);
    p = fmaf(p, r, -0.284496736f);
    p = fmaf(p, r, 0.254829592f);
    p = p * r;
    const float erfz = 1.0f - p * e;
    return 0.5f * t * (1.0f + copysignf(erfz, t));
}

// ---------------------------------------------------------------------------
// Kernel 1: sparse adjacency build (one wave per row) + weight folding
// (unchanged from the validated round-6/7 kernel)
// ---------------------------------------------------------------------------
__global__ __launch_bounds__(64) void prep_kernel(
    const float* __restrict__ nodevec,   // [512,10]
    const float* __restrict__ nodeveck,  // [1,10]
    const float* __restrict__ w_start,   // [16,1]
    const float* __restrict__ b_start,   // [16]
    const float* __restrict__ w_mlp,     // [16,48]
    const float* __restrict__ b_mlp,     // [16]
    const float* __restrict__ w_end,     // [1,16]
    const float* __restrict__ b_end,     // [1]
    int*   __restrict__ wsI,
    float* __restrict__ wsF)
{
    const int v    = blockIdx.x;
    const int lane = threadIdx.x;

    if (v == N_NODES) {
        if (lane < SC) {
            const int o = lane;
            float u0 = 0.f, u1 = 0.f, u2 = 0.f, bt = b_mlp[o];
            for (int c = 0; c < CC; ++c) {
                const float ws = w_start[c];
                const float bs = b_start[c];
                const float m0 = w_mlp[o * 48 + c];
                const float m1 = w_mlp[o * 48 + 16 + c];
                const float m2 = w_mlp[o * 48 + 32 + c];
                u0 += m0 * ws; u1 += m1 * ws; u2 += m2 * ws;
                bt += (m0 + m1 + m2) * bs;
            }
            wsF[OFF_U + 0 * 16 + o] = u0;
            wsF[OFF_U + 1 * 16 + o] = u1;
            wsF[OFF_U + 2 * 16 + o] = u2;
            wsF[OFF_BETA + o]       = bt;
            wsF[OFF_WEND + o]       = w_end[o];
            if (o == 0) wsF[OFF_BEND] = b_end[0];
        }
        return;
    }

    float q[NDIM];
    #pragma unroll
    for (int d = 0; d < NDIM; ++d) {
        const float k = nodeveck[d];
        q[d] = nodevec[v * NDIM + d] * k * k;
    }

    float s[8];
    int   wi[8];
    #pragma unroll
    for (int j = 0; j < 8; ++j) {
        const int w = lane + 64 * j;
        wi[j] = w;
        float dot = 0.f;
        #pragma unroll
        for (int d = 0; d < NDIM; ++d) dot += q[d] * nodevec[w * NDIM + d];
        s[j] = dot > 0.f ? dot : 0.f;
    }

    float m = s[0];
    #pragma unroll
    for (int j = 1; j < 8; ++j) m = fmaxf(m, s[j]);
    for (int off = 32; off; off >>= 1) m = fmaxf(m, __shfl_down(m, off));
    m = __shfl(m, 0);

    float zs = 0.f;
    #pragma unroll
    for (int j = 0; j < 8; ++j) zs += expf(s[j] - m);
    for (int off = 32; off; off >>= 1) zs += __shfl_down(zs, off);
    zs = __shfl(zs, 0);

    float sl[8];
    #pragma unroll
    for (int j = 0; j < 8; ++j) sl[j] = s[j];

    float topv[TOPK];
    int   topi[TOPK];
    for (int t = 0; t < TOPK; ++t) {
        float bv = -1.f; int bi = N_NODES;
        #pragma unroll
        for (int j = 0; j < 8; ++j) {
            if (sl[j] > bv || (sl[j] == bv && wi[j] < bi)) { bv = sl[j]; bi = wi[j]; }
        }
        for (int off = 32; off; off >>= 1) {
            const float ov = __shfl_down(bv, off);
            const int   oi = __shfl_down(bi, off);
            if (ov > bv || (ov == bv && oi < bi)) { bv = ov; bi = oi; }
        }
        bv = __shfl(bv, 0); bi = __shfl(bi, 0);
        topv[t] = bv; topi[t] = bi;
        #pragma unroll
        for (int j = 0; j < 8; ++j) if (wi[j] == bi) sl[j] = -1.f;
    }

    if (lane == 0) {
        float p[TOPK], rs = 1.f;  // +1 from the identity self-loop
        #pragma unroll
        for (int t = 0; t < TOPK; ++t) { p[t] = expf(topv[t] - m) / zs; rs += p[t]; }
        const float inv = 1.f / rs;
        #pragma unroll
        for (int t = 0; t < TOPK; ++t) {
            wsI[t * N_NODES + v]          = topi[t];
            wsF[OFF_NW + t * N_NODES + v] = p[t] * inv;
        }
        wsF[OFF_WSELF + v] = inv;
    }
}

// ---------------------------------------------------------------------------
// Kernel 2 (restructured): ONE ROW PER WAVE, zero __syncthreads.
// Each wave owns 2 private 512-float LDS buffers; lane owns nodes j*64+lane.
// Wave-synchronous LDS exchange: ds ops from one wave complete in order;
// explicit s_waitcnt lgkmcnt(0) + wave_barrier fence each write->read phase.
// LN is a pure 64-lane shfl_xor butterfly. MLP constants are wave-uniform
// scalar loads (no LDS staging).
// ---------------------------------------------------------------------------
__global__ __launch_bounds__(256, 4) void graphblock_kernel(
    const float* __restrict__ x,         // [B, L, N]
    const float* __restrict__ ln_gamma,  // [N]
    const float* __restrict__ ln_beta,   // [N]
    const int*   __restrict__ wsI,
    const float* __restrict__ wsF,
    float*       __restrict__ out)       // [B, L, N]
{
    __shared__ float lds[WAVES_PER_BLOCK * 2 * N_NODES];   // 16 KB

    const int tid  = threadIdx.x;
    const int lane = tid & 63;
    const int wid  = tid >> 6;
    const int row  = blockIdx.x * WAVES_PER_BLOCK + wid;   // b*SEQ + l

    float* buf0 = &lds[wid * 2 * N_NODES];
    float* buf1 = buf0 + N_NODES;

    const float* xr = x + (size_t)row * N_NODES;

    // ---- load per-node state: x0, packed gather indices, weights ----
    float x0[NODES_PER_LANE];
    unsigned int p01[NODES_PER_LANE], p23[NODES_PER_LANE];
    float a0[NODES_PER_LANE], a1[NODES_PER_LANE], a2[NODES_PER_LANE],
          a3[NODES_PER_LANE], asf[NODES_PER_LANE];

    #pragma unroll
    for (int j = 0; j < NODES_PER_LANE; ++j) {
        const int v = j * 64 + lane;
        x0[j] = xr[v];
        const unsigned int i0 = (unsigned int)wsI[0 * N_NODES + v];
        const unsigned int i1 = (unsigned int)wsI[1 * N_NODES + v];
        const unsigned int i2 = (unsigned int)wsI[2 * N_NODES + v];
        const unsigned int i3 = (unsigned int)wsI[3 * N_NODES + v];
        p01[j] = i0 | (i1 << 16);
        p23[j] = i2 | (i3 << 16);
        a0[j]  = wsF[OFF_NW + 0 * N_NODES + v];
        a1[j]  = wsF[OFF_NW + 1 * N_NODES + v];
        a2[j]  = wsF[OFF_NW + 2 * N_NODES + v];
        a3[j]  = wsF[OFF_NW + 3 * N_NODES + v];
        asf[j] = wsF[OFF_WSELF + v];
        buf0[v] = x0[j];
    }
    // fence: all 64 lanes' buf0 writes complete before any gather reads
    asm volatile("s_waitcnt lgkmcnt(0)" ::: "memory");
    __builtin_amdgcn_wave_barrier();

    const float OMA = 1.f - ALPHA;

    // ---- diffusion step 1: gather x0, write x1 into buf1 ----
    float x1[NODES_PER_LANE];
    #pragma unroll
    for (int j = 0; j < NODES_PER_LANE; ++j) {
        const float g = a0[j] * buf0[p01[j] & 0xffffu]
                      + a1[j] * buf0[p01[j] >> 16]
                      + a2[j] * buf0[p23[j] & 0xffffu]
                      + a3[j] * buf0[p23[j] >> 16]
                      + asf[j] * x0[j];
        x1[j] = ALPHA * x0[j] + OMA * g;
        buf1[j * 64 + lane] = x1[j];
    }
    asm volatile("s_waitcnt lgkmcnt(0)" ::: "memory");
    __builtin_amdgcn_wave_barrier();

    // ---- wave-uniform folded-MLP constants (scalar loads) ----
    // (addresses are tid-independent -> s_load into SGPRs)
    const float bend = wsF[OFF_BEND];

    // ---- diffusion step 2 + fused MLP/GELU/end-conv per node ----
    float yv[NODES_PER_LANE];
    #pragma unroll
    for (int j = 0; j < NODES_PER_LANE; ++j) {
        const float g = a0[j] * buf1[p01[j] & 0xffffu]
                      + a1[j] * buf1[p01[j] >> 16]
                      + a2[j] * buf1[p23[j] & 0xffffu]
                      + a3[j] * buf1[p23[j] >> 16]
                      + asf[j] * x1[j];
        const float x2 = ALPHA * x0[j] + OMA * g;

        float acc = bend;
        #pragma unroll
        for (int o = 0; o < SC; ++o) {
            const float t = wsF[OFF_U + o]          * x0[j]
                          + wsF[OFF_U + 16 + o]     * x1[j]
                          + wsF[OFF_U + 32 + o]     * x2
                          + wsF[OFF_BETA + o];
            acc = fmaf(wsF[OFF_WEND + o], gelu_exact_fast(t), acc);
        }
        yv[j] = x0[j] + acc;
    }

    // ---- LayerNorm over the wave's 512 nodes: butterfly, no LDS ----
    float s = 0.f, q = 0.f;
    #pragma unroll
    for (int j = 0; j < NODES_PER_LANE; ++j) { s += yv[j]; q += yv[j] * yv[j]; }
    #pragma unroll
    for (int off = 32; off; off >>= 1) {
        s += __shfl_xor(s, off);
        q += __shfl_xor(q, off);
    }
    const float mu   = s * (1.f / (float)N_NODES);
    const float var  = q * (1.f / (float)N_NODES) - mu * mu;
    const float rstd = 1.0f / sqrtf(var + LN_EPS);

    float* orow = out + (size_t)row * N_NODES;
    #pragma unroll
    for (int j = 0; j < NODES_PER_LANE; ++j) {
        const int v = j * 64 + lane;
        orow[v] = (yv[j] - mu) * rstd * ln_gamma[v] + ln_beta[v];
    }
}

// ---------------------------------------------------------------------------
extern "C" void kernel_launch(void* const* d_in, const int* in_sizes, int n_in,
                              void* d_out, int out_size, void* d_ws, size_t ws_size,
                              hipStream_t stream) {
    const float* x        = (const float*)d_in[0];
    const float* nodevec  = (const float*)d_in[1];
    const float* nodeveck = (const float*)d_in[2];
    const float* w_start  = (const float*)d_in[3];
    const float* b_start  = (const float*)d_in[4];
    const float* w_mlp    = (const float*)d_in[5];
    const float* b_mlp    = (const float*)d_in[6];
    const float* w_end    = (const float*)d_in[7];
    const float* b_end    = (const float*)d_in[8];
    const float* ln_gamma = (const float*)d_in[9];
    const float* ln_beta  = (const float*)d_in[10];

    int*   wsI = (int*)d_ws;
    float* wsF = (float*)d_ws;

    prep_kernel<<<N_NODES + 1, 64, 0, stream>>>(
        nodevec, nodeveck, w_start, b_start, w_mlp, b_mlp, w_end, b_end, wsI, wsF);

    graphblock_kernel<<<(BATCH * SEQ) / WAVES_PER_BLOCK, 256, 0, stream>>>(
        x, ln_gamma, ln_beta, (const int*)d_ws, (const float*)d_ws, (float*)d_out);
}